// Round 4
// baseline (387.934 us; speedup 1.0000x reference)
//
#include <hip/hip_runtime.h>
#include <hip/hip_bf16.h>

typedef __attribute__((ext_vector_type(8))) short short8;
typedef __attribute__((ext_vector_type(4))) float floatx4;
typedef __attribute__((ext_vector_type(16))) float floatx16;

#define B_    4
#define S_    2048
#define EMB_  1024
#define NH_   16
#define HD_   64

#if __has_builtin(__builtin_amdgcn_exp2f)
#define EXP2F(x) __builtin_amdgcn_exp2f(x)
#else
#define EXP2F(x) exp2f(x)
#endif

__device__ __forceinline__ void async_cp16(const void* g, void* l) {
  __builtin_amdgcn_global_load_lds(
      (const __attribute__((address_space(1))) unsigned int*)g,
      (__attribute__((address_space(3))) unsigned int*)l, 16, 0, 0);
}

__device__ __forceinline__ ushort4 cvt4(const float4 f) {
  __bf16 t[4] = {(__bf16)f.x, (__bf16)f.y, (__bf16)f.z, (__bf16)f.w};
  return *(const ushort4*)t;
}

// One-shot fp32 -> bf16 conversion of x, Wq|Wk|Wv (stacked into Wcat), Wo,
// plus fp32 bias packing bq|bk|bv -> bcat. 4 elems/thread.
__global__ __launch_bounds__(256)
void cvt_kernel(const float* __restrict__ x,
                const float* __restrict__ wq, const float* __restrict__ wk,
                const float* __restrict__ wv, const float* __restrict__ wo,
                const float* __restrict__ bq, const float* __restrict__ bk,
                const float* __restrict__ bv,
                __bf16* __restrict__ xb, __bf16* __restrict__ Wcat,
                __bf16* __restrict__ Wob, float* __restrict__ bcat)
{
  const int NX4 = 2097152;   // 8388608/4
  const int NW4 = 262144;    // 1048576/4
  int g = blockIdx.x * 256 + threadIdx.x;
  if (g < NX4) {
    *(ushort4*)(xb + (size_t)g * 4) = cvt4(*(const float4*)(x + (size_t)g * 4));
    return;
  }
  g -= NX4;
  if (g < 3 * NW4) {   // Wcat = [Wq; Wk; Wv] row-stacked
    const float* src = (g < NW4) ? wq : (g < 2 * NW4) ? wk : wv;
    const int gg = (g < NW4) ? g : (g < 2 * NW4) ? g - NW4 : g - 2 * NW4;
    *(ushort4*)(Wcat + (size_t)g * 4) = cvt4(*(const float4*)(src + (size_t)gg * 4));
    return;
  }
  g -= 3 * NW4;
  if (g < NW4) {
    *(ushort4*)(Wob + (size_t)g * 4) = cvt4(*(const float4*)(wo + (size_t)g * 4));
    return;
  }
  g -= NW4;
  if (g < 768) {       // bcat = [bq; bk; bv] fp32
    const float* src = (g < 256) ? bq : (g < 512) ? bk : bv;
    *(float4*)(bcat + (size_t)g * 4) = *(const float4*)(src + (size_t)(g & 255) * 4);
  }
}

// Fused QKV: C[8192,3072] = xb @ Wcat^T + bcat, all bf16, global_load_lds staging.
// n<1024 -> Q (scaled by SCL*log2e) BHSD; n<2048 -> K BHSD; else -> V^T BHDS.
__global__ __launch_bounds__(256)
void gemm_qkv_kernel(const __bf16* __restrict__ A, const __bf16* __restrict__ W,
                     const float* __restrict__ bcat,
                     __bf16* __restrict__ Qb, __bf16* __restrict__ Kb,
                     __bf16* __restrict__ Vb)
{
  __shared__ __attribute__((aligned(16))) __bf16 As[128 * 32];
  __shared__ __attribute__((aligned(16))) __bf16 Ws[128 * 32];
  const int tid  = threadIdx.x;
  const int wave = tid >> 6, lane = tid & 63;
  const int l15  = lane & 15, quad = lane >> 4;
  const int wm   = wave >> 1, wn = wave & 1;
  const int bm   = blockIdx.y * 128;
  const int bn   = blockIdx.x * 128;        // 0..2944
  const int widx = bn >> 10;                // 0=Q 1=K 2=V (block-uniform)
  const float QS = 0.180336880f;            // (1/sqrt(64)) * log2(e)

  floatx4 acc[4][4];
#pragma unroll
  for (int i = 0; i < 4; ++i)
#pragma unroll
    for (int j = 0; j < 4; ++j) acc[i][j] = (floatx4){0.f, 0.f, 0.f, 0.f};

  const int srow = tid >> 2;          // 0..63
  const int scol = (tid & 3) << 3;    // 0,8,16,24
  const __bf16* Ag = A + (size_t)(bm + srow) * 1024 + scol;
  const __bf16* Wg = W + (size_t)(bn + srow) * 1024 + scol;
  __bf16* AsD = As + tid * 8;
  __bf16* WsD = Ws + tid * 8;

  for (int k0 = 0; k0 < 1024; k0 += 32) {
    __syncthreads();
    async_cp16(Ag + k0,             AsD);
    async_cp16(Ag + k0 + 64 * 1024, AsD + 2048);
    async_cp16(Wg + k0,             WsD);
    async_cp16(Wg + k0 + 64 * 1024, WsD + 2048);
    __syncthreads();
    short8 af[4], wf[4];
#pragma unroll
    for (int mi = 0; mi < 4; ++mi)
      af[mi] = *(const short8*)(As + ((wm * 64 + mi * 16 + l15) << 5) + (quad << 3));
#pragma unroll
    for (int ni = 0; ni < 4; ++ni)
      wf[ni] = *(const short8*)(Ws + ((wn * 64 + ni * 16 + l15) << 5) + (quad << 3));
#pragma unroll
    for (int mi = 0; mi < 4; ++mi)
#pragma unroll
      for (int ni = 0; ni < 4; ++ni)
        acc[mi][ni] = __builtin_amdgcn_mfma_f32_16x16x32_bf16(af[mi], wf[ni], acc[mi][ni], 0, 0, 0);
  }

#pragma unroll
  for (int ni = 0; ni < 4; ++ni) {
    const int n  = bn + wn * 64 + ni * 16 + l15;
    const float bvb = bcat[n];
    const int np = n & 1023;
    const int h = np >> 6, d = np & 63;
#pragma unroll
    for (int mi = 0; mi < 4; ++mi) {
      const int m0 = bm + wm * 64 + mi * 16 + quad * 4;
      const int b = m0 >> 11, s0 = m0 & 2047;
      floatx4 v = acc[mi][ni];
      if (widx == 0) {
        const size_t base = (size_t)(b * 16 + h) * (S_ * 64) + d;
#pragma unroll
        for (int r = 0; r < 4; ++r)
          Qb[base + (size_t)(s0 + r) * 64] = (__bf16)((v[r] + bvb) * QS);
      } else if (widx == 1) {
        const size_t base = (size_t)(b * 16 + h) * (S_ * 64) + d;
#pragma unroll
        for (int r = 0; r < 4; ++r)
          Kb[base + (size_t)(s0 + r) * 64] = (__bf16)(v[r] + bvb);
      } else {
        const size_t base = ((size_t)(b * 16 + h) * 64 + d) * S_ + s0;
        union { ushort4 u4; unsigned short u[4]; } pk;
#pragma unroll
        for (int r = 0; r < 4; ++r) {
          __bf16 hv = (__bf16)(v[r] + bvb);
          pk.u[r] = *(unsigned short*)&hv;
        }
        *(ushort4*)(Vb + base) = pk.u4;    // 8B aligned: s0 % 4 == 0
      }
    }
  }
}

// Flash attention, causal, exp2-domain (Q pre-scaled by SCL*log2e).
// 32x32x16 MFMA engine: block = 2 waves (128 thr), each wave owns 32 q-rows.
// Grid (16, 64): block serially processes paired 64-row q-tiles {qtA, 31-qtA}
// -> 33 k-tile iterations, balanced across blocks (4 blocks/CU, all resident).
// SWAPPED OPERANDS: S^T = mfma(K, Q): A-frag = K rows (k = kv), B-frag = Q^T
// (lane col q = lane&31). Lane owns ONE q-row with 32 k-values split across
// the lane-half pair (h = lane>>5): k = sub*32 + (reg&3)+8*(reg>>2)+4h.
// Softmax lane-local (31 fmax + 1 shfl_xor(32)); T13 defer-max; P -> Ps LDS
// (per-wave, wave-local lgkm drain); PV: O^T = mfma(V^T, P^T).
// T14 async-STAGE: next tile's K/V global loads issued after staging barrier.
// Output IN-PLACE over Q (block-owned rows). LDS 27.6 KB -> 4 blocks/CU.
__global__ __launch_bounds__(128, 2)
void attn_kernel(__bf16* __restrict__ Q, const __bf16* __restrict__ K,
                 const __bf16* __restrict__ Vt)
{
  __shared__ __attribute__((aligned(16))) __bf16 Ks[64 * 72];
  __shared__ __attribute__((aligned(16))) __bf16 Vs[64 * 72];   // V^T: [d][kv]
  __shared__ __attribute__((aligned(16))) __bf16 Ps[2][32 * 72];

  const int tid  = threadIdx.x;
  const int wave = tid >> 6, lane = tid & 63;
  const int l31  = lane & 31, h = lane >> 5;
  const int qtA  = blockIdx.x, bh = blockIdx.y;
  const size_t hb = (size_t)bh * (S_ * 64);
  const float MASKV = -1.0e30f;

  const int srow = tid >> 1;          // 0..63
  const int scol = (tid & 1) << 5;    // 0,32

  for (int qsel = 0; qsel < 2; ++qsel) {
    const int qt = qsel ? (31 - qtA) : qtA;
    const int myq = qt * 64 + wave * 32 + l31;   // this lane's q row

    // Q fragments in registers: B-operand Q^T[c][q=l31]; c = s*16 + h*8 + j
    short8 aq[4];
#pragma unroll
    for (int s = 0; s < 4; ++s)
      aq[s] = *(const short8*)(Q + hb + (size_t)myq * 64 + s * 16 + h * 8);

    floatx16 oacc[2];                 // O^T: d = dt*32 + (r&3)+8*(r>>2)+4h, q = l31
#pragma unroll
    for (int dt = 0; dt < 2; ++dt)
#pragma unroll
      for (int r = 0; r < 16; ++r) oacc[dt][r] = 0.f;
    float lsum = 0.0f;
    float mrun = MASKV;

    // prologue: issue kt=0 tile loads into regs (T14 issue-early)
    uint4 kreg[4], vreg[4];
    {
      const __bf16* kp = K  + hb + (size_t)srow * 64 + scol;
      const __bf16* vp = Vt + hb + (size_t)srow * S_ + scol;
#pragma unroll
      for (int u = 0; u < 4; ++u) {
        kreg[u] = *(const uint4*)(kp + u * 8);
        vreg[u] = *(const uint4*)(vp + u * 8);
      }
    }

    for (int kt = 0; kt <= qt; ++kt) {
      __syncthreads();                      // all waves done reading prev tile
#pragma unroll
      for (int u = 0; u < 4; ++u) {
        *(uint4*)(&Ks[srow * 72 + scol + u * 8]) = kreg[u];
        *(uint4*)(&Vs[srow * 72 + scol + u * 8]) = vreg[u];
      }
      __syncthreads();                      // tile staged

      if (kt < qt) {                        // issue kt+1 loads; hide under compute
        const __bf16* kp = K  + hb + (size_t)((kt + 1) * 64 + srow) * 64 + scol;
        const __bf16* vp = Vt + hb + (size_t)srow * S_ + (kt + 1) * 64 + scol;
#pragma unroll
        for (int u = 0; u < 4; ++u) {
          kreg[u] = *(const uint4*)(kp + u * 8);
          vreg[u] = *(const uint4*)(vp + u * 8);
        }
      }

      // S^T = K Q^T: two 32-kv subtiles, K-dim d=64 in 4 steps of 16
      floatx16 sacc[2];
#pragma unroll
      for (int sub = 0; sub < 2; ++sub)
#pragma unroll
        for (int r = 0; r < 16; ++r) sacc[sub][r] = 0.f;
#pragma unroll
      for (int s = 0; s < 4; ++s) {
        short8 ak0 = *(const short8*)(&Ks[(l31)      * 72 + s * 16 + h * 8]);
        short8 ak1 = *(const short8*)(&Ks[(32 + l31) * 72 + s * 16 + h * 8]);
        sacc[0] = __builtin_amdgcn_mfma_f32_32x32x16_bf16(ak0, aq[s], sacc[0], 0, 0, 0);
        sacc[1] = __builtin_amdgcn_mfma_f32_32x32x16_bf16(ak1, aq[s], sacc[1], 0, 0, 0);
      }

      // causal mask (diagonal tile only): k_global > q -> MASKV
      if (kt == qt) {
#pragma unroll
        for (int sub = 0; sub < 2; ++sub)
#pragma unroll
          for (int r = 0; r < 16; ++r) {
            const int kg = kt * 64 + sub * 32 + (r & 3) + 8 * (r >> 2) + 4 * h;
            if (kg > myq) sacc[sub][r] = MASKV;
          }
      }

      // lane-local max over 32 k-values, then cross-half reduce (same q row)
      float tmax = MASKV;
#pragma unroll
      for (int sub = 0; sub < 2; ++sub)
#pragma unroll
        for (int r = 0; r < 16; ++r) tmax = fmaxf(tmax, sacc[sub][r]);
      tmax = fmaxf(tmax, __shfl_xor(tmax, 32));

      const float mold = mrun;
      if (!__all(tmax <= mold + 8.0f)) {    // T13 defer-max: rescale only if needed
        const float mnew = fmaxf(mold, tmax);
        const float alpha = EXP2F(mold - mnew);
#pragma unroll
        for (int dt = 0; dt < 2; ++dt)
#pragma unroll
          for (int r = 0; r < 16; ++r) oacc[dt][r] *= alpha;
        lsum *= alpha;
        mrun = mnew;
      }
      const float m = mrun;

      // P = exp2(S - m): 8x ds_write_b64 into per-wave Ps[q=l31][k]
      float psum = 0.f;
#pragma unroll
      for (int sub = 0; sub < 2; ++sub)
#pragma unroll
        for (int m4 = 0; m4 < 4; ++m4) {
          float4 p;
          p.x = EXP2F(sacc[sub][4 * m4 + 0] - m);
          p.y = EXP2F(sacc[sub][4 * m4 + 1] - m);
          p.z = EXP2F(sacc[sub][4 * m4 + 2] - m);
          p.w = EXP2F(sacc[sub][4 * m4 + 3] - m);
          psum += (p.x + p.y) + (p.z + p.w);
          *(ushort4*)(&Ps[wave][l31 * 72 + sub * 32 + 8 * m4 + 4 * h]) = cvt4(p);
        }
      lsum += psum;

      // Ps is per-wave: wave-local LDS drain instead of __syncthreads
      asm volatile("s_waitcnt lgkmcnt(0)" ::: "memory");
      __builtin_amdgcn_sched_barrier(0);

      // O^T += V^T P^T: kv in 4 steps of 16; A = V^T rows (d), B = P^T (q=l31)
#pragma unroll
      for (int st = 0; st < 4; ++st) {
        const short8 pf = *(const short8*)(&Ps[wave][l31 * 72 + st * 16 + h * 8]);
        short8 av0 = *(const short8*)(&Vs[(l31)      * 72 + st * 16 + h * 8]);
        short8 av1 = *(const short8*)(&Vs[(32 + l31) * 72 + st * 16 + h * 8]);
        oacc[0] = __builtin_amdgcn_mfma_f32_32x32x16_bf16(av0, pf, oacc[0], 0, 0, 0);
        oacc[1] = __builtin_amdgcn_mfma_f32_32x32x16_bf16(av1, pf, oacc[1], 0, 0, 0);
      }
    }

    // epilogue: l(q) = lane partial + half-partner partial
    float l = lsum + __shfl_xor(lsum, 32);
    const float inv = 1.0f / fmaxf(l, 1e-20f);
    const size_t rowb = hb + (size_t)myq * 64;
#pragma unroll
    for (int dt = 0; dt < 2; ++dt)
#pragma unroll
      for (int m4 = 0; m4 < 4; ++m4) {
        float4 o;
        o.x = oacc[dt][4 * m4 + 0] * inv;
        o.y = oacc[dt][4 * m4 + 1] * inv;
        o.z = oacc[dt][4 * m4 + 2] * inv;
        o.w = oacc[dt][4 * m4 + 3] * inv;
        *(ushort4*)(Q + rowb + dt * 32 + 8 * m4 + 4 * h) = cvt4(o);  // 8B aligned
      }
  }
}

// Final projection: A = attn output (bf16, BHSD gather), W = Wob bf16,
// bias fp32, out fp32 row-major. global_load_lds staging.
__global__ __launch_bounds__(256)
void gemm_o_kernel(const __bf16* __restrict__ A, const __bf16* __restrict__ W,
                   const float* __restrict__ bias, float* __restrict__ out)
{
  __shared__ __attribute__((aligned(16))) __bf16 As[128 * 32];
  __shared__ __attribute__((aligned(16))) __bf16 Ws[128 * 32];
  const int tid  = threadIdx.x;
  const int wave = tid >> 6, lane = tid & 63;
  const int l15  = lane & 15, quad = lane >> 4;
  const int wm   = wave >> 1, wn = wave & 1;
  const int bm   = blockIdx.y * 128;
  const int bn   = blockIdx.x * 128;

  floatx4 acc[4][4];
#pragma unroll
  for (int i = 0; i < 4; ++i)
#pragma unroll
    for (int j = 0; j < 4; ++j) acc[i][j] = (floatx4){0.f, 0.f, 0.f, 0.f};

  const int srow = tid >> 2;
  const int scol = (tid & 3) << 3;
  const __bf16* Wg = W + (size_t)(bn + srow) * 1024 + scol;
  const int bb = bm >> 11;                 // batch
  const int ss = (bm & 2047) + srow;       // seq
  __bf16* AsD = As + tid * 8;
  __bf16* WsD = Ws + tid * 8;

  for (int k0 = 0; k0 < 1024; k0 += 32) {
    const int c = k0 + scol, hh = c >> 6, dd = c & 63;  // 8 elems never cross a head
    const __bf16* pa0 = A + (((size_t)(bb * 16 + hh) * S_) + ss) * 64 + dd;
    __syncthreads();
    async_cp16(pa0,           AsD);
    async_cp16(pa0 + 64 * 64, AsD + 2048);             // s -> s+64
    async_cp16(Wg + k0,             WsD);
    async_cp16(Wg + k0 + 64 * 1024, WsD + 2048);
    __syncthreads();

    short8 af[4], wf[4];
#pragma unroll
    for (int mi = 0; mi < 4; ++mi)
      af[mi] = *(const short8*)(As + ((wm * 64 + mi * 16 + l15) << 5) + (quad << 3));
#pragma unroll
    for (int ni = 0; ni < 4; ++ni)
      wf[ni] = *(const short8*)(Ws + ((wn * 64 + ni * 16 + l15) << 5) + (quad << 3));
#pragma unroll
    for (int mi = 0; mi < 4; ++mi)
#pragma unroll
      for (int ni = 0; ni < 4; ++ni)
        acc[mi][ni] = __builtin_amdgcn_mfma_f32_16x16x32_bf16(af[mi], wf[ni], acc[mi][ni], 0, 0, 0);
  }

#pragma unroll
  for (int ni = 0; ni < 4; ++ni) {
    const int n = bn + wn * 64 + ni * 16 + l15;
    const float bvb = bias[n];
#pragma unroll
    for (int mi = 0; mi < 4; ++mi) {
      const int m0 = bm + wm * 64 + mi * 16 + quad * 4;
      floatx4 v = acc[mi][ni];
#pragma unroll
      for (int r = 0; r < 4; ++r)
        out[(size_t)(m0 + r) * 1024 + n] = v[r] + bvb;
    }
  }
}

extern "C" void kernel_launch(void* const* d_in, const int* in_sizes, int n_in,
                              void* d_out, int out_size, void* d_ws, size_t ws_size,
                              hipStream_t stream) {
  const float* x  = (const float*)d_in[0];
  const float* Wq = (const float*)d_in[1];
  const float* bq = (const float*)d_in[2];
  const float* Wk = (const float*)d_in[3];
  const float* bk = (const float*)d_in[4];
  const float* Wv = (const float*)d_in[5];
  const float* bv = (const float*)d_in[6];
  const float* Wo = (const float*)d_in[7];
  const float* bo = (const float*)d_in[8];
  // d_in[9] = causal_mask (int32) — causality implemented analytically, unused.

  const size_t BUF = (size_t)B_ * NH_ * S_ * HD_;   // 8388608 elems
  __bf16* ws   = (__bf16*)d_ws;                     // ws usage: ~42 MB
  __bf16* xb   = ws;                                // 8388608  (16.8 MB)
  __bf16* Wcat = ws + 8388608;                      // 3145728  (6 MB)
  __bf16* Wob  = ws + 11534336;                     // 1048576  (2 MB)
  __bf16* Qb   = ws + 12582912;                     // 8388608  (16.8 MB)
  float*  bcat = (float*)(ws + 20971520);           // 3072 fp32 (12 KB)
  __bf16* Kb   = (__bf16*)d_out;                    // d_out reused as K+V^T
  __bf16* Vb   = (__bf16*)d_out + BUF;              // scratch until attn done

  cvt_kernel<<<12291, dim3(256), 0, stream>>>(x, Wq, Wk, Wv, Wo, bq, bk, bv,
                                              xb, Wcat, Wob, bcat);
  gemm_qkv_kernel<<<dim3(24, 64), dim3(256), 0, stream>>>(xb, Wcat, bcat, Qb, Kb, Vb);
  attn_kernel<<<dim3(16, 64), dim3(128), 0, stream>>>(Qb, Kb, Vb);
  gemm_o_kernel<<<dim3(8, 64), dim3(256), 0, stream>>>(Qb, Wob, bo, (float*)d_out);
}